// Round 1
// 1094.209 us; speedup vs baseline: 1.0931x; 1.0931x over previous
//
#include <hip/hip_runtime.h>
#include <math.h>

#define NCLS 19
#define NPROTO 10
#define KM 190
#define KMP 192
#define D 720
#define BM 128
#define NCHK 15

typedef __bf16 bf16x8 __attribute__((ext_vector_type(8)));
typedef float f32x16 __attribute__((ext_vector_type(16)));

__device__ __forceinline__ float wred_sum(float v) {
#pragma unroll
  for (int o = 32; o > 0; o >>= 1) v += __shfl_xor(v, o, 64);
  return v;
}
__device__ __forceinline__ float wred_max(float v) {
#pragma unroll
  for (int o = 32; o > 0; o >>= 1) v = fmaxf(v, __shfl_xor(v, o, 64));
  return v;
}
__device__ __forceinline__ double wred_sumd(double v) {
#pragma unroll
  for (int o = 32; o > 0; o >>= 1) v += __shfl_xor(v, o, 64);
  return v;
}

// bf16 RTNE high part; returns bits, writes back the fp32 value of hi
__device__ __forceinline__ ushort bf_hi(float v, float& hf) {
  const uint u = __float_as_uint(v);
  const uint r = (u + 0x7FFFu + ((u >> 16) & 1u)) >> 16;
  hf = __uint_as_float(r << 16);
  return (ushort)r;
}

// ---------------- prep: G2[d]=g^2, GB[d]=g*b, C3={Sum g^2, Sum g b, Sum b^2}
__global__ void prep_gb(const float* __restrict__ fg, const float* __restrict__ fb,
                        float* __restrict__ G2, float* __restrict__ GB,
                        float* __restrict__ C3) {
  const int t = threadIdx.x;
  float cg = 0.f, cgb = 0.f, cb = 0.f;
  for (int d2 = t; d2 < D; d2 += 256) {
    const float g = fg[d2], b = fb[d2];
    G2[d2] = g * g;
    GB[d2] = g * b;
    cg = fmaf(g, g, cg);
    cgb = fmaf(g, b, cgb);
    cb = fmaf(b, b, cb);
  }
  __shared__ float red[3][4];
  cg = wred_sum(cg); cgb = wred_sum(cgb); cb = wred_sum(cb);
  const int w = t >> 6, lane = t & 63;
  if (lane == 0) { red[0][w] = cg; red[1][w] = cgb; red[2][w] = cb; }
  __syncthreads();
  if (t == 0) {
    C3[0] = red[0][0] + red[0][1] + red[0][2] + red[0][3];
    C3[1] = red[1][0] + red[1][1] + red[1][2] + red[1][3];
    C3[2] = red[2][0] + red[2][1] + red[2][2] + red[2][3];
  }
}

// ---------------- proto prep: split g*Phat into bf16 hi/lo, laid out in the
// exact per-chunk LDS staging order: pgtb[c][src][kb][col][8] with
// d = c*48 + kb*8 + e.  Also A[j]=Sum g*Phat, B[j]=Sum b*Phat (fp32).
__global__ void proto_prep(const float* __restrict__ pr, const float* __restrict__ fg,
                           const float* __restrict__ fb, ushort* __restrict__ pgtb,
                           float* __restrict__ Av, float* __restrict__ Bv) {
  const int j = blockIdx.x, lane = threadIdx.x;
  if (j >= KM) {  // zero pad columns 190,191
#pragma unroll
    for (int jj = 0; jj < 12; ++jj) {
      const int d2 = lane + 64 * jj;
      if (d2 < D) {
        const int c = d2 / 48, kb = (d2 >> 3) % 6, e = d2 & 7;
        const size_t off0 = ((((size_t)c * 2 + 0) * 6 + kb) * KMP + j) * 8 + e;
        const size_t off1 = ((((size_t)c * 2 + 1) * 6 + kb) * KMP + j) * 8 + e;
        pgtb[off0] = 0; pgtb[off1] = 0;
      }
    }
    if (lane == 0) { Av[j] = 0.f; Bv[j] = 0.f; }
    return;
  }
  float pv[12];
  float sp = 0.f;
#pragma unroll
  for (int jj = 0; jj < 12; ++jj) {
    const int d2 = lane + 64 * jj;
    pv[jj] = (d2 < D) ? pr[(size_t)j * D + d2] : 0.f;
    sp = fmaf(pv[jj], pv[jj], sp);
  }
  sp = wred_sum(sp);
  const float ip = 1.f / fmaxf(sqrtf(sp), 1e-12f);
  float sa = 0.f, sb = 0.f;
#pragma unroll
  for (int jj = 0; jj < 12; ++jj) {
    const int d2 = lane + 64 * jj;
    if (d2 < D) {
      const float ph = pv[jj] * ip;
      const float g = fg[d2], b = fb[d2];
      const float val = g * ph;
      float hf, dummy;
      const ushort h = bf_hi(val, hf);
      const ushort l = bf_hi(val - hf, dummy);
      const int c = d2 / 48, kb = (d2 >> 3) % 6, e = d2 & 7;
      const size_t off0 = ((((size_t)c * 2 + 0) * 6 + kb) * KMP + j) * 8 + e;
      const size_t off1 = ((((size_t)c * 2 + 1) * 6 + kb) * KMP + j) * 8 + e;
      pgtb[off0] = h; pgtb[off1] = l;
      sa = fmaf(g, ph, sa);
      sb = fmaf(b, ph, sb);
    }
  }
  sa = wred_sum(sa); sb = wred_sum(sb);
  if (lane == 0) { Av[j] = sa; Bv[j] = sb; }
}

// ---------------- main pass: split-bf16 MFMA GEMM + per-pixel affine fixup + epilogue
// acc = xhi*phi + xhi*plo + xlo*phi  (error ~2^-18, below fp32 reorder noise)
__global__ __launch_bounds__(256, 1) void gemm_main(
    const float* __restrict__ x, const ushort* __restrict__ pgtb,
    const float* __restrict__ Av, const float* __restrict__ Bv,
    const float* __restrict__ G2, const float* __restrict__ GB,
    const float* __restrict__ C3, const int* __restrict__ gt,
    float* __restrict__ out_seg, float* __restrict__ contrast,
    float* __restrict__ se, int* __restrict__ flags,
    const float* __restrict__ mn_g, const float* __restrict__ mn_b,
    const float* __restrict__ pn_g, const float* __restrict__ pn_b, int N) {
  __shared__ __align__(16) union {
    struct {
      ushort X[2][2][6][BM][8];   // [buf][src][kb][pix][8]   49152 B
      ushort P[2][2][6][KMP][8];  // [buf][src][kb][col][8]   73728 B
    } g;
    float SIM[BM][KMP];           // 98304 B (epilogue reuse)
  } U;
  __shared__ float A_s[KMP], B_s[KMP];
  __shared__ float PGn[KMP], PBn[KMP];
  __shared__ float MGn[32], MBn[32];
  __shared__ float MU[BM], RS[BM], IL[BM];
  __shared__ float ST[5][2][BM];

  const int t = threadIdx.x;
  const int n0 = blockIdx.x * BM;
  const int w = t >> 6, lane = t & 63;
  const int wm = w >> 1, wn = w & 1;      // wave tile: rows [64*wm,+64), cols [96*wn,+96)
  const int l31 = lane & 31, lhi = lane >> 5;
  const int spix = t & 127, skb0 = t >> 7;  // staging: pixel, kb parity

  if (t < KMP) {
    A_s[t] = Av[t]; B_s[t] = Bv[t];
    PGn[t] = (t < KM) ? pn_g[t] : 0.f;
    PBn[t] = (t < KM) ? pn_b[t] : 0.f;
  }
  if (t < NCLS) { MGn[t] = mn_g[t]; MBn[t] = mn_b[t]; }

  f32x16 acc[2][3];
#pragma unroll
  for (int mr = 0; mr < 2; ++mr)
#pragma unroll
    for (int nt = 0; nt < 3; ++nt)
#pragma unroll
      for (int e = 0; e < 16; ++e) acc[mr][nt][e] = 0.f;

  float s0 = 0.f, qq = 0.f, s1 = 0.f, s2 = 0.f, s3 = 0.f;

  const float* xbase = x + (size_t)(n0 + spix) * D;
  const uint4* pbase = (const uint4*)pgtb;  // chunk c at pbase + c*2304

  float4 xa[3], xb[3];
  uint4 pv[9];

  auto loadX = [&](int cc) {
#pragma unroll
    for (int jj = 0; jj < 3; ++jj) {
      const int kb = skb0 + 2 * jj;
      const float4* p4 = (const float4*)(xbase + cc * 48 + kb * 8);
      xa[jj] = p4[0];
      xb[jj] = p4[1];
    }
  };
  auto loadP = [&](int cc) {
    const uint4* ps = pbase + (size_t)cc * 2304;
#pragma unroll
    for (int i = 0; i < 9; ++i) pv[i] = ps[t + 256 * i];
  };
  auto stageWrite = [&](int bf, int cc) {
    uint4* pd = (uint4*)&U.g.P[bf][0][0][0][0];
#pragma unroll
    for (int i = 0; i < 9; ++i) pd[t + 256 * i] = pv[i];
#pragma unroll
    for (int jj = 0; jj < 3; ++jj) {
      const int kb = skb0 + 2 * jj;
      const int d0 = cc * 48 + kb * 8;
      const float v[8] = {xa[jj].x, xa[jj].y, xa[jj].z, xa[jj].w,
                          xb[jj].x, xb[jj].y, xb[jj].z, xb[jj].w};
      const float4 g2a = *(const float4*)&G2[d0];
      const float4 g2b = *(const float4*)&G2[d0 + 4];
      const float4 gba = *(const float4*)&GB[d0];
      const float4 gbb = *(const float4*)&GB[d0 + 4];
      const float gg[8] = {g2a.x, g2a.y, g2a.z, g2a.w, g2b.x, g2b.y, g2b.z, g2b.w};
      const float gv[8] = {gba.x, gba.y, gba.z, gba.w, gbb.x, gbb.y, gbb.z, gbb.w};
      ushort h[8], l[8];
#pragma unroll
      for (int e = 0; e < 8; ++e) {
        const float xv = v[e];
        float hf, dummy;
        h[e] = bf_hi(xv, hf);
        l[e] = bf_hi(xv - hf, dummy);
        s0 += xv;
        const float xx = xv * xv;
        qq += xx;
        s1 = fmaf(xv, gg[e], s1);
        s2 = fmaf(xx, gg[e], s2);
        s3 = fmaf(xv, gv[e], s3);
      }
      *(uint4*)&U.g.X[bf][0][kb][spix][0] =
          make_uint4((uint)h[0] | ((uint)h[1] << 16), (uint)h[2] | ((uint)h[3] << 16),
                     (uint)h[4] | ((uint)h[5] << 16), (uint)h[6] | ((uint)h[7] << 16));
      *(uint4*)&U.g.X[bf][1][kb][spix][0] =
          make_uint4((uint)l[0] | ((uint)l[1] << 16), (uint)l[2] | ((uint)l[3] << 16),
                     (uint)l[4] | ((uint)l[5] << 16), (uint)l[6] | ((uint)l[7] << 16));
    }
  };
  auto mfmaStep = [&](int bf) {
#pragma unroll
    for (int ks = 0; ks < 3; ++ks) {
      const int kb = 2 * ks + lhi;  // lane supplies k = 8*lhi+e of this 16-slice
      bf16x8 ah[2], al[2], bh[3], bl[3];
#pragma unroll
      for (int mr = 0; mr < 2; ++mr) {
        const int row = 64 * wm + 32 * mr + l31;
        ah[mr] = *reinterpret_cast<const bf16x8*>(&U.g.X[bf][0][kb][row][0]);
        al[mr] = *reinterpret_cast<const bf16x8*>(&U.g.X[bf][1][kb][row][0]);
      }
#pragma unroll
      for (int nt = 0; nt < 3; ++nt) {
        const int col = 96 * wn + 32 * nt + l31;
        bh[nt] = *reinterpret_cast<const bf16x8*>(&U.g.P[bf][0][kb][col][0]);
        bl[nt] = *reinterpret_cast<const bf16x8*>(&U.g.P[bf][1][kb][col][0]);
      }
#pragma unroll
      for (int mr = 0; mr < 2; ++mr)
#pragma unroll
        for (int nt = 0; nt < 3; ++nt)
          acc[mr][nt] = __builtin_amdgcn_mfma_f32_32x32x16_bf16(ah[mr], bh[nt],
                                                                acc[mr][nt], 0, 0, 0);
#pragma unroll
      for (int mr = 0; mr < 2; ++mr)
#pragma unroll
        for (int nt = 0; nt < 3; ++nt)
          acc[mr][nt] = __builtin_amdgcn_mfma_f32_32x32x16_bf16(ah[mr], bl[nt],
                                                                acc[mr][nt], 0, 0, 0);
#pragma unroll
      for (int mr = 0; mr < 2; ++mr)
#pragma unroll
        for (int nt = 0; nt < 3; ++nt)
          acc[mr][nt] = __builtin_amdgcn_mfma_f32_32x32x16_bf16(al[mr], bh[nt],
                                                                acc[mr][nt], 0, 0, 0);
    }
  };

  // prologue: stage chunk 0 into buf 0
  loadX(0);
  loadP(0);
  stageWrite(0, 0);
  __syncthreads();

  for (int c = 0; c < NCHK; ++c) {
    const int buf = c & 1;
    if (c + 1 < NCHK) { loadX(c + 1); loadP(c + 1); }  // in flight under MFMA
    mfmaStep(buf);
    if (c + 1 < NCHK) stageWrite(buf ^ 1, c + 1);
    __syncthreads();
  }

  // per-pixel stats reduction (2 threads per pixel)
  ST[0][skb0][spix] = s0;
  ST[1][skb0][spix] = qq;
  ST[2][skb0][spix] = s1;
  ST[3][skb0][spix] = s2;
  ST[4][skb0][spix] = s3;
  __syncthreads();
  if (t < BM) {
    const float S0 = ST[0][0][t] + ST[0][1][t];
    const float Q = ST[1][0][t] + ST[1][1][t];
    const float S1 = ST[2][0][t] + ST[2][1][t];
    const float S2 = ST[3][0][t] + ST[3][1][t];
    const float S3 = ST[4][0][t] + ST[4][1][t];
    const float Cgg = C3[0], Cgb = C3[1], Cbb = C3[2];
    const float mu = S0 / 720.f;
    const float var = Q / 720.f - mu * mu;
    const float rs = 1.f / sqrtf(var + 1e-5f);
    const float L2v = rs * rs * (S2 - 2.f * mu * S1 + mu * mu * Cgg) +
                      2.f * rs * (S3 - mu * Cgb) + Cbb;
    MU[t] = mu;
    RS[t] = rs;
    IL[t] = 1.f / fmaxf(sqrtf(fmaxf(L2v, 0.f)), 1e-12f);
  }
  __syncthreads();

  // fixup to true cosine sims, write SIM (unions over the staging buffers)
  float aC[3], bC[3];
#pragma unroll
  for (int nt = 0; nt < 3; ++nt) {
    const int col = 96 * wn + 32 * nt + l31;
    aC[nt] = A_s[col];
    bC[nt] = B_s[col];
  }
#pragma unroll
  for (int mr = 0; mr < 2; ++mr)
#pragma unroll
    for (int rg = 0; rg < 16; ++rg) {
      const int pix = 64 * wm + 32 * mr + (rg & 3) + 8 * (rg >> 2) + 4 * lhi;
      const float mu = MU[pix], rs = RS[pix], il = IL[pix];
#pragma unroll
      for (int nt = 0; nt < 3; ++nt) {
        const int col = 96 * wn + 32 * nt + l31;
        U.SIM[pix][col] = (rs * (acc[mr][nt][rg] - mu * aC[nt]) + bC[nt]) * il;
      }
    }
  __syncthreads();

  // epilogue: wave w handles pixels 32w..32w+31
  const int j0 = lane, j1 = lane + 64, j2 = lane + 128;
  const bool ok2 = (j2 < KM);
  for (int pi = 0; pi < 32; ++pi) {
    const int pix = w * 32 + pi;
    const int n = n0 + pix;
    const float sv0 = U.SIM[pix][j0];
    const float sv1 = U.SIM[pix][j1];
    const float sv2 = ok2 ? U.SIM[pix][j2] : 0.f;
    // LN over 190 -> contrast_logits
    float sum = sv0 + sv1 + sv2;
    sum = wred_sum(sum);
    const float mu = sum / 190.f;
    const float d0v = sv0 - mu, d1v = sv1 - mu, d2v = ok2 ? (sv2 - mu) : 0.f;
    float vs = d0v * d0v + d1v * d1v + d2v * d2v;
    vs = wred_sum(vs);
    const float rstd = 1.f / sqrtf(vs / 190.f + 1e-5f);
    contrast[(size_t)n * KM + j0] = d0v * rstd * PGn[j0] + PBn[j0];
    contrast[(size_t)n * KM + j1] = d1v * rstd * PGn[j1] + PBn[j1];
    if (ok2) contrast[(size_t)n * KM + j2] = d2v * rstd * PGn[j2] + PBn[j2];
    // stash this pixel's own-class sims
    const int g0 = gt[n];
    const int b10 = g0 * 10;
    if (j0 >= b10 && j0 < b10 + 10) se[(size_t)n * 10 + (j0 - b10)] = sv0;
    if (j1 >= b10 && j1 < b10 + 10) se[(size_t)n * 10 + (j1 - b10)] = sv1;
    if (ok2 && j2 >= b10 && j2 < b10 + 10) se[(size_t)n * 10 + (j2 - b10)] = sv2;
    // per-class max + LN over 19 -> out_seg, pred
    float mx = -3.0e38f;
    if (lane < NCLS) {
      const float* row = &U.SIM[pix][lane * 10];
#pragma unroll
      for (int m2 = 0; m2 < 10; ++m2) mx = fmaxf(mx, row[m2]);
    }
    float s19 = wred_sum(lane < NCLS ? mx : 0.f);
    const float mu19 = s19 / 19.f;
    const float dv = (lane < NCLS) ? (mx - mu19) : 0.f;
    float v19 = wred_sum(dv * dv);
    const float rs19 = 1.f / sqrtf(v19 / 19.f + 1e-5f);
    float key = -3.0e38f;
    if (lane < NCLS) {
      const float os = dv * rs19 * MGn[lane] + MBn[lane];
      out_seg[(size_t)n * NCLS + lane] = os;
      key = os;
    }
    const float kmax = wred_max(key);
    const unsigned long long bm = __ballot(key == kmax);
    const int pred = __ffsll((unsigned long long)bm) - 1;
    if (lane == 0) flags[n] = (pred == g0) ? 1 : 0;
  }
}

// ---------------- Sinkhorn column-sum pass (one iteration's numerator)
__global__ void sk_colsum(const float* __restrict__ se, const int* __restrict__ gt,
                          const float* __restrict__ u, float* __restrict__ partials,
                          int iter, int nblk, int N) {
  __shared__ float Sl[KMP];
  const int t = threadIdx.x;
  if (t < KMP) Sl[t] = 0.f;
  __syncthreads();
  const int n = blockIdx.x * 256 + t;
  if (n < N) {
    const int b10 = gt[n] * 10;
    float e[10];
#pragma unroll
    for (int m = 0; m < 10; ++m) e[m] = expf(se[(size_t)n * 10 + m] / 0.05f);
    float a = 1.f;
    if (iter > 0) {
      float s = 0.f;
#pragma unroll
      for (int m = 0; m < 10; ++m) s += e[m] * u[b10 + m];
      a = (s > 0.f) ? 1.f / s : 0.f;
    }
#pragma unroll
    for (int m = 0; m < 10; ++m) atomicAdd(&Sl[b10 + m], a * e[m]);
  }
  __syncthreads();
  if (t < KM) partials[(size_t)t * nblk + blockIdx.x] = Sl[t];
}

__global__ void sk_reduce(const float* __restrict__ partials, float* __restrict__ u,
                          int nblk) {
  const int j = blockIdx.x, lane = threadIdx.x;
  double s = 0.0;
  for (int b = lane; b < nblk; b += 64) s += (double)partials[(size_t)j * nblk + b];
  s = wred_sumd(s);
  if (lane == 0) u[j] = (s > 0.0) ? (float)(1.0 / (10.0 * s)) : 0.f;
}

__global__ void sk_final(const float* __restrict__ se, const int* __restrict__ gt,
                         const float* __restrict__ u, const int* __restrict__ flags,
                         float* __restrict__ ptgt, int* __restrict__ list,
                         int* __restrict__ cnt, int* __restrict__ n_km, int N) {
  const int n = blockIdx.x * 256 + threadIdx.x;
  if (n >= N) return;
  const int g0 = gt[n], b10 = g0 * 10;
  float best = -1.f;
  int bi = 0;
#pragma unroll
  for (int m = 0; m < 10; ++m) {
    const float v = expf(se[(size_t)n * 10 + m] / 0.05f) * u[b10 + m];
    if (v > best) { best = v; bi = m; }
  }
  ptgt[n] = (float)(bi + 10 * g0);
  if (flags[n]) {
    atomicAdd(&n_km[b10 + bi], 1);
    const int p = atomicAdd(cnt, 1);
    list[p] = n | (bi << 20) | (g0 << 24);
  }
}

// ---------------- f accumulation over correct pixels (wave per pixel)
__global__ void f_accum(const float* __restrict__ x, const float* __restrict__ fg,
                        const float* __restrict__ fb, const int* __restrict__ list,
                        const int* __restrict__ cnt, float* __restrict__ f) {
  const int lane = threadIdx.x & 63;
  const int wid = (blockIdx.x * blockDim.x + threadIdx.x) >> 6;
  const int nw = (gridDim.x * blockDim.x) >> 6;
  const int total = *cnt;
  for (int i = wid; i < total; i += nw) {
    const int packed = list[i];
    const int n = packed & 0xFFFFF;
    const int m = (packed >> 20) & 0xF;
    const int k = (packed >> 24) & 0x1F;
    float xv[12];
    float s0 = 0.f, q = 0.f;
#pragma unroll
    for (int jj = 0; jj < 12; ++jj) {
      const int d2 = lane + 64 * jj;
      xv[jj] = (d2 < D) ? x[(size_t)n * D + d2] : 0.f;
      s0 += xv[jj];
      q = fmaf(xv[jj], xv[jj], q);
    }
    s0 = wred_sum(s0);
    q = wred_sum(q);
    const float mu = s0 / 720.f;
    const float var = q / 720.f - mu * mu;
    const float rs = 1.f / sqrtf(var + 1e-5f);
    float cv[12];
    float l2 = 0.f;
#pragma unroll
    for (int jj = 0; jj < 12; ++jj) {
      const int d2 = lane + 64 * jj;
      if (d2 < D) {
        cv[jj] = (xv[jj] - mu) * rs * fg[d2] + fb[d2];
        l2 = fmaf(cv[jj], cv[jj], l2);
      } else {
        cv[jj] = 0.f;
      }
    }
    l2 = wred_sum(l2);
    const float il = 1.f / fmaxf(sqrtf(l2), 1e-12f);
    float* frow = &f[(size_t)(k * 10 + m) * D];
#pragma unroll
    for (int jj = 0; jj < 12; ++jj) {
      const int d2 = lane + 64 * jj;
      if (d2 < D) atomicAdd(&frow[d2], cv[jj] * il);
    }
  }
}

// ---------------- prototype update (one wave per proto row)
__global__ void protos_out(const float* __restrict__ pr, const float* __restrict__ f,
                           const int* __restrict__ n_km, float* __restrict__ out) {
  const int j = blockIdx.x, lane = threadIdx.x;
  float pv[12], fv[12];
  float sp = 0.f, sf = 0.f;
#pragma unroll
  for (int jj = 0; jj < 12; ++jj) {
    const int d2 = lane + 64 * jj;
    pv[jj] = (d2 < D) ? pr[(size_t)j * D + d2] : 0.f;
    fv[jj] = (d2 < D) ? f[(size_t)j * D + d2] : 0.f;
    sp = fmaf(pv[jj], pv[jj], sp);
    sf = fmaf(fv[jj], fv[jj], sf);
  }
  sp = wred_sum(sp);
  sf = wred_sum(sf);
  const float ip = 1.f / fmaxf(sqrtf(sp), 1e-12f);
  const float iff = 1.f / fmaxf(sqrtf(sf), 1e-12f);
  const bool valid = n_km[j] > 0;
  float vv[12];
  float sv = 0.f;
#pragma unroll
  for (int jj = 0; jj < 12; ++jj) {
    const float ph = pv[jj] * ip;
    vv[jj] = valid ? (0.999f * ph + 0.001f * (fv[jj] * iff)) : ph;
    sv = fmaf(vv[jj], vv[jj], sv);
  }
  sv = wred_sum(sv);
  const float ivv = 1.f / fmaxf(sqrtf(sv), 1e-12f);
#pragma unroll
  for (int jj = 0; jj < 12; ++jj) {
    const int d2 = lane + 64 * jj;
    if (d2 < D) out[(size_t)j * D + d2] = vv[jj] * ivv;
  }
}

extern "C" void kernel_launch(void* const* d_in, const int* in_sizes, int n_in,
                              void* d_out, int out_size, void* d_ws, size_t ws_size,
                              hipStream_t stream) {
  const float* x = (const float*)d_in[0];
  const float* protos = (const float*)d_in[1];
  const float* fn_g = (const float*)d_in[2];
  const float* fn_b = (const float*)d_in[3];
  const float* mn_g = (const float*)d_in[4];
  const float* mn_b = (const float*)d_in[5];
  const float* pn_g = (const float*)d_in[6];
  const float* pn_b = (const float*)d_in[7];
  const int* gt = (const int*)d_in[8];
  const int N = in_sizes[0] / D;

  float* out_seg = (float*)d_out;
  float* contrast = out_seg + (size_t)N * NCLS;
  float* ptgt = contrast + (size_t)N * KM;
  float* pnew = ptgt + (size_t)N;

  char* ws = (char*)d_ws;
  size_t off = 0;
  auto alloc = [&](size_t bytes) {
    char* p = ws + off;
    off = (off + bytes + 255) & ~(size_t)255;
    return p;
  };
  const int nblk = (N + 255) / 256;
  ushort* pgtb = (ushort*)alloc((size_t)NCHK * 2 * 6 * KMP * 8 * 2);  // 552960 B
  float* Av = (float*)alloc(KMP * 4);
  float* Bv = (float*)alloc(KMP * 4);
  float* G2 = (float*)alloc(D * 4);
  float* GB = (float*)alloc(D * 4);
  float* C3 = (float*)alloc(4 * 4);
  float* se = (float*)alloc((size_t)N * 10 * 4);
  float* partials = (float*)alloc((size_t)KM * nblk * 4);
  float* u = (float*)alloc(KMP * 4);
  float* f = (float*)alloc((size_t)KM * D * 4);
  int* n_km = (int*)alloc(KMP * 4);
  int* flags = (int*)alloc((size_t)N * 4);
  int* list = (int*)alloc((size_t)N * 4);
  int* cnt = (int*)alloc(256);

  hipMemsetAsync(f, 0, (size_t)KM * D * 4, stream);
  hipMemsetAsync(n_km, 0, KMP * 4, stream);
  hipMemsetAsync(cnt, 0, 4, stream);

  prep_gb<<<1, 256, 0, stream>>>(fn_g, fn_b, G2, GB, C3);
  proto_prep<<<KMP, 64, 0, stream>>>(protos, fn_g, fn_b, pgtb, Av, Bv);
  gemm_main<<<N / BM, 256, 0, stream>>>(x, pgtb, Av, Bv, G2, GB, C3, gt, out_seg,
                                        contrast, se, flags, mn_g, mn_b, pn_g,
                                        pn_b, N);
  for (int it = 0; it < 3; ++it) {
    sk_colsum<<<nblk, 256, 0, stream>>>(se, gt, u, partials, it, nblk, N);
    sk_reduce<<<KM, 64, 0, stream>>>(partials, u, nblk);
  }
  sk_final<<<nblk, 256, 0, stream>>>(se, gt, u, flags, ptgt, list, cnt, n_km, N);
  f_accum<<<256, 256, 0, stream>>>(x, fn_g, fn_b, list, cnt, f);
  protos_out<<<KM, 64, 0, stream>>>(protos, f, n_km, pnew);
}

// Round 2
// 861.476 us; speedup vs baseline: 1.3884x; 1.2702x over previous
//
#include <hip/hip_runtime.h>
#include <math.h>

#define NCLS 19
#define NPROTO 10
#define KM 190
#define KMP 192
#define D 720
#define BM 64
#define CHK 16
#define NCHK 45

typedef __bf16 bf16x8 __attribute__((ext_vector_type(8)));
typedef float f32x16 __attribute__((ext_vector_type(16)));

__device__ __forceinline__ float wred_sum(float v) {
#pragma unroll
  for (int o = 32; o > 0; o >>= 1) v += __shfl_xor(v, o, 64);
  return v;
}
__device__ __forceinline__ float wred_max(float v) {
#pragma unroll
  for (int o = 32; o > 0; o >>= 1) v = fmaxf(v, __shfl_xor(v, o, 64));
  return v;
}
__device__ __forceinline__ double wred_sumd(double v) {
#pragma unroll
  for (int o = 32; o > 0; o >>= 1) v += __shfl_xor(v, o, 64);
  return v;
}

// bf16 RTNE high part; returns bits, writes back the fp32 value of hi
__device__ __forceinline__ ushort bf_hi(float v, float& hf) {
  const uint u = __float_as_uint(v);
  const uint r = (u + 0x7FFFu + ((u >> 16) & 1u)) >> 16;
  hf = __uint_as_float(r << 16);
  return (ushort)r;
}

// ---------------- prep: G2[d]=g^2, GB[d]=g*b, C3={Sum g^2, Sum g b, Sum b^2}
__global__ void prep_gb(const float* __restrict__ fg, const float* __restrict__ fb,
                        float* __restrict__ G2, float* __restrict__ GB,
                        float* __restrict__ C3) {
  const int t = threadIdx.x;
  float cg = 0.f, cgb = 0.f, cb = 0.f;
  for (int d2 = t; d2 < D; d2 += 256) {
    const float g = fg[d2], b = fb[d2];
    G2[d2] = g * g;
    GB[d2] = g * b;
    cg = fmaf(g, g, cg);
    cgb = fmaf(g, b, cgb);
    cb = fmaf(b, b, cb);
  }
  __shared__ float red[3][4];
  cg = wred_sum(cg); cgb = wred_sum(cgb); cb = wred_sum(cb);
  const int w = t >> 6, lane = t & 63;
  if (lane == 0) { red[0][w] = cg; red[1][w] = cgb; red[2][w] = cb; }
  __syncthreads();
  if (t == 0) {
    C3[0] = red[0][0] + red[0][1] + red[0][2] + red[0][3];
    C3[1] = red[1][0] + red[1][1] + red[1][2] + red[1][3];
    C3[2] = red[2][0] + red[2][1] + red[2][2] + red[2][3];
  }
}

// ---------------- proto prep: split g*Phat into bf16 hi/lo, laid out per
// 16-wide K-chunk in the exact LDS staging order:
// offset(ushort) = c*6144 + ((src*2+kb)*192 + col)*8 + e, d = c*16 + kb*8 + e.
// Also A[j]=Sum g*Phat, B[j]=Sum b*Phat (fp32).
__global__ void proto_prep(const float* __restrict__ pr, const float* __restrict__ fg,
                           const float* __restrict__ fb, ushort* __restrict__ pgtb,
                           float* __restrict__ Av, float* __restrict__ Bv) {
  const int j = blockIdx.x, lane = threadIdx.x;
  if (j >= KM) {  // zero pad columns 190,191
#pragma unroll
    for (int jj = 0; jj < 12; ++jj) {
      const int d2 = lane + 64 * jj;
      if (d2 < D) {
        const int c = d2 >> 4, kb = (d2 >> 3) & 1, e = d2 & 7;
        const size_t b0 = (size_t)c * 6144 + (size_t)kb * KMP * 8 + (size_t)j * 8 + e;
        pgtb[b0] = 0;                      // src 0 (hi)
        pgtb[b0 + 2 * KMP * 8] = 0;        // src 1 (lo)
      }
    }
    if (lane == 0) { Av[j] = 0.f; Bv[j] = 0.f; }
    return;
  }
  float pv[12];
  float sp = 0.f;
#pragma unroll
  for (int jj = 0; jj < 12; ++jj) {
    const int d2 = lane + 64 * jj;
    pv[jj] = (d2 < D) ? pr[(size_t)j * D + d2] : 0.f;
    sp = fmaf(pv[jj], pv[jj], sp);
  }
  sp = wred_sum(sp);
  const float ip = 1.f / fmaxf(sqrtf(sp), 1e-12f);
  float sa = 0.f, sb = 0.f;
#pragma unroll
  for (int jj = 0; jj < 12; ++jj) {
    const int d2 = lane + 64 * jj;
    if (d2 < D) {
      const float ph = pv[jj] * ip;
      const float g = fg[d2], b = fb[d2];
      const float val = g * ph;
      float hf, dummy;
      const ushort h = bf_hi(val, hf);
      const ushort l = bf_hi(val - hf, dummy);
      const int c = d2 >> 4, kb = (d2 >> 3) & 1, e = d2 & 7;
      const size_t b0 = (size_t)c * 6144 + (size_t)kb * KMP * 8 + (size_t)j * 8 + e;
      pgtb[b0] = h;
      pgtb[b0 + 2 * KMP * 8] = l;
      sa = fmaf(g, ph, sa);
      sb = fmaf(b, ph, sb);
    }
  }
  sa = wred_sum(sa); sb = wred_sum(sb);
  if (lane == 0) { Av[j] = sa; Bv[j] = sb; }
}

// ---------------- main pass: split-bf16 MFMA GEMM + per-pixel affine fixup + epilogue
// acc = xhi*phi + xhi*plo + xlo*phi  (error ~2^-18, below fp32 reorder noise)
// BM=64, K-chunk=16, 4 waves (2m x 2n, 32x96 wave tile), 3 blocks/CU.
__global__ __launch_bounds__(256, 3) void gemm_main(
    const float* __restrict__ x, const ushort* __restrict__ pgtb,
    const float* __restrict__ Av, const float* __restrict__ Bv,
    const float* __restrict__ G2, const float* __restrict__ GB,
    const float* __restrict__ C3, const int* __restrict__ gt,
    float* __restrict__ out_seg, float* __restrict__ contrast,
    float* __restrict__ se, int* __restrict__ flags,
    const float* __restrict__ mn_g, const float* __restrict__ mn_b,
    const float* __restrict__ pn_g, const float* __restrict__ pn_b, int N) {
  __shared__ __align__(16) union {
    struct {
      ushort X[2][2][2][BM][8];   // [buf][src][kb][pix][8]   8192 B
      ushort P[2][2][2][KMP][8];  // [buf][src][kb][col][8]  24576 B
    } g;
    float ST[5][4][BM];           // stats partials (aliased, 5120 B)
    float SIM[BM][KMP];           // 49152 B (epilogue reuse)
  } U;
  __shared__ float A_s[KMP], B_s[KMP];
  __shared__ float PGn[KMP], PBn[KMP];
  __shared__ float MGn[32], MBn[32];
  __shared__ float MU[BM], RS[BM], IL[BM];

  const int t = threadIdx.x;
  const int n0 = blockIdx.x * BM;
  const int w = t >> 6, lane = t & 63;
  const int wm = w >> 1, wn = w & 1;  // wave tile: rows [32*wm,+32), cols [96*wn,+96)
  const int l31 = lane & 31, lhi = lane >> 5;
  const int pix = t & 63, q = t >> 6;  // staging: pixel, d-quad

  if (t < KMP) {
    A_s[t] = Av[t]; B_s[t] = Bv[t];
    PGn[t] = (t < KM) ? pn_g[t] : 0.f;
    PBn[t] = (t < KM) ? pn_b[t] : 0.f;
  }
  if (t < NCLS) { MGn[t] = mn_g[t]; MBn[t] = mn_b[t]; }

  f32x16 acc[3];
#pragma unroll
  for (int nt = 0; nt < 3; ++nt)
#pragma unroll
    for (int e = 0; e < 16; ++e) acc[nt][e] = 0.f;

  float s0 = 0.f, qq = 0.f, s1 = 0.f, s2 = 0.f, s3 = 0.f;

  const float* xrow = x + (size_t)(n0 + pix) * D + 4 * q;
  const int kb0 = q >> 1, e0 = (q & 1) * 4;

  // conversion + stats + LDS write of one X quad (4 floats of d = c*16+4q)
  auto stageX = [&](int nb, const float4& xv, const float4& g2, const float4& gb) {
    const float vs4[4] = {xv.x, xv.y, xv.z, xv.w};
    const float g2s[4] = {g2.x, g2.y, g2.z, g2.w};
    const float gbs[4] = {gb.x, gb.y, gb.z, gb.w};
    ushort h[4], l[4];
#pragma unroll
    for (int e = 0; e < 4; ++e) {
      const float v = vs4[e];
      float hf, dm;
      h[e] = bf_hi(v, hf);
      l[e] = bf_hi(v - hf, dm);
      s0 += v;
      const float xx = v * v;
      qq += xx;
      s1 = fmaf(v, g2s[e], s1);
      s2 = fmaf(xx, g2s[e], s2);
      s3 = fmaf(v, gbs[e], s3);
    }
    *(ushort4*)&U.g.X[nb][0][kb0][pix][e0] = make_ushort4(h[0], h[1], h[2], h[3]);
    *(ushort4*)&U.g.X[nb][1][kb0][pix][e0] = make_ushort4(l[0], l[1], l[2], l[3]);
  };

  auto mfmaStep = [&](int bf) {
    const int row = 32 * wm + l31;
    const bf16x8 ah = *reinterpret_cast<const bf16x8*>(&U.g.X[bf][0][lhi][row][0]);
    const bf16x8 al = *reinterpret_cast<const bf16x8*>(&U.g.X[bf][1][lhi][row][0]);
    bf16x8 bh[3], bl[3];
#pragma unroll
    for (int nt = 0; nt < 3; ++nt) {
      const int col = 96 * wn + 32 * nt + l31;
      bh[nt] = *reinterpret_cast<const bf16x8*>(&U.g.P[bf][0][lhi][col][0]);
      bl[nt] = *reinterpret_cast<const bf16x8*>(&U.g.P[bf][1][lhi][col][0]);
    }
#pragma unroll
    for (int nt = 0; nt < 3; ++nt)
      acc[nt] = __builtin_amdgcn_mfma_f32_32x32x16_bf16(ah, bh[nt], acc[nt], 0, 0, 0);
#pragma unroll
    for (int nt = 0; nt < 3; ++nt)
      acc[nt] = __builtin_amdgcn_mfma_f32_32x32x16_bf16(ah, bl[nt], acc[nt], 0, 0, 0);
#pragma unroll
    for (int nt = 0; nt < 3; ++nt)
      acc[nt] = __builtin_amdgcn_mfma_f32_32x32x16_bf16(al, bh[nt], acc[nt], 0, 0, 0);
  };

  // prologue: stage chunk 0 into buf 0
  {
    const uint4* ps = (const uint4*)pgtb;
    const uint4 p0 = ps[t], p1 = ps[t + 256], p2 = ps[t + 512];
    const float4 xv = *(const float4*)xrow;
    const float4 g2 = *(const float4*)&G2[4 * q];
    const float4 gb = *(const float4*)&GB[4 * q];
    uint4* pd = (uint4*)&U.g.P[0][0][0][0][0];
    pd[t] = p0; pd[t + 256] = p1; pd[t + 512] = p2;
    stageX(0, xv, g2, gb);
  }
  __syncthreads();

  for (int c = 0; c < NCHK; ++c) {
    const int buf = c & 1;
    uint4 p0, p1, p2;
    float4 xv, g2, gb;
    const bool pf = (c + 1 < NCHK);
    if (pf) {
      const uint4* ps = (const uint4*)(pgtb + (size_t)(c + 1) * 6144);
      p0 = ps[t]; p1 = ps[t + 256]; p2 = ps[t + 512];
      xv = *(const float4*)(xrow + (c + 1) * CHK);
      const int d0 = (c + 1) * CHK + 4 * q;
      g2 = *(const float4*)&G2[d0];
      gb = *(const float4*)&GB[d0];
    }
    mfmaStep(buf);
    if (pf) {
      uint4* pd = (uint4*)&U.g.P[buf ^ 1][0][0][0][0];
      pd[t] = p0; pd[t + 256] = p1; pd[t + 512] = p2;
      stageX(buf ^ 1, xv, g2, gb);
    }
    __syncthreads();
  }

  // per-pixel stats reduction (4 threads per pixel); ST aliases staging (done)
  U.ST[0][q][pix] = s0;
  U.ST[1][q][pix] = qq;
  U.ST[2][q][pix] = s1;
  U.ST[3][q][pix] = s2;
  U.ST[4][q][pix] = s3;
  __syncthreads();
  if (t < BM) {
    float S0 = 0.f, Q = 0.f, S1 = 0.f, S2 = 0.f, S3 = 0.f;
#pragma unroll
    for (int s = 0; s < 4; ++s) {
      S0 += U.ST[0][s][t];
      Q += U.ST[1][s][t];
      S1 += U.ST[2][s][t];
      S2 += U.ST[3][s][t];
      S3 += U.ST[4][s][t];
    }
    const float Cgg = C3[0], Cgb = C3[1], Cbb = C3[2];
    const float mu = S0 / 720.f;
    const float var = Q / 720.f - mu * mu;
    const float rs = 1.f / sqrtf(var + 1e-5f);
    const float L2v = rs * rs * (S2 - 2.f * mu * S1 + mu * mu * Cgg) +
                      2.f * rs * (S3 - mu * Cgb) + Cbb;
    MU[t] = mu;
    RS[t] = rs;
    IL[t] = 1.f / fmaxf(sqrtf(fmaxf(L2v, 0.f)), 1e-12f);
  }
  __syncthreads();

  // fixup to true cosine sims, write SIM (aliases ST + staging; both dead)
#pragma unroll
  for (int nt = 0; nt < 3; ++nt) {
    const int col = 96 * wn + 32 * nt + l31;
    const float aC = A_s[col], bC = B_s[col];
#pragma unroll
    for (int rg = 0; rg < 16; ++rg) {
      const int pr = 32 * wm + (rg & 3) + 8 * (rg >> 2) + 4 * lhi;
      U.SIM[pr][col] = (RS[pr] * (acc[nt][rg] - MU[pr] * aC) + bC) * IL[pr];
    }
  }
  __syncthreads();

  // epilogue: wave w handles pixels 16w..16w+15
  const int j0 = lane, j1 = lane + 64, j2 = lane + 128;
  const bool ok2 = (j2 < KM);
  for (int pi = 0; pi < 16; ++pi) {
    const int px = w * 16 + pi;
    const int n = n0 + px;
    const float sv0 = U.SIM[px][j0];
    const float sv1 = U.SIM[px][j1];
    const float sv2 = ok2 ? U.SIM[px][j2] : 0.f;
    // LN over 190 -> contrast_logits
    float sum = sv0 + sv1 + sv2;
    sum = wred_sum(sum);
    const float mu = sum / 190.f;
    const float d0v = sv0 - mu, d1v = sv1 - mu, d2v = ok2 ? (sv2 - mu) : 0.f;
    float vs = d0v * d0v + d1v * d1v + d2v * d2v;
    vs = wred_sum(vs);
    const float rstd = 1.f / sqrtf(vs / 190.f + 1e-5f);
    contrast[(size_t)n * KM + j0] = d0v * rstd * PGn[j0] + PBn[j0];
    contrast[(size_t)n * KM + j1] = d1v * rstd * PGn[j1] + PBn[j1];
    if (ok2) contrast[(size_t)n * KM + j2] = d2v * rstd * PGn[j2] + PBn[j2];
    // stash this pixel's own-class sims
    const int g0 = gt[n];
    const int b10 = g0 * 10;
    if (j0 >= b10 && j0 < b10 + 10) se[(size_t)n * 10 + (j0 - b10)] = sv0;
    if (j1 >= b10 && j1 < b10 + 10) se[(size_t)n * 10 + (j1 - b10)] = sv1;
    if (ok2 && j2 >= b10 && j2 < b10 + 10) se[(size_t)n * 10 + (j2 - b10)] = sv2;
    // per-class max + LN over 19 -> out_seg, pred
    float mx = -3.0e38f;
    if (lane < NCLS) {
      const float* row = &U.SIM[px][lane * 10];
#pragma unroll
      for (int m2 = 0; m2 < 10; ++m2) mx = fmaxf(mx, row[m2]);
    }
    float s19 = wred_sum(lane < NCLS ? mx : 0.f);
    const float mu19 = s19 / 19.f;
    const float dv = (lane < NCLS) ? (mx - mu19) : 0.f;
    float v19 = wred_sum(dv * dv);
    const float rs19 = 1.f / sqrtf(v19 / 19.f + 1e-5f);
    float key = -3.0e38f;
    if (lane < NCLS) {
      const float os = dv * rs19 * MGn[lane] + MBn[lane];
      out_seg[(size_t)n * NCLS + lane] = os;
      key = os;
    }
    const float kmax = wred_max(key);
    const unsigned long long bm = __ballot(key == kmax);
    const int pred = __ffsll((unsigned long long)bm) - 1;
    if (lane == 0) flags[n] = (pred == g0) ? 1 : 0;
  }
}

// ---------------- Sinkhorn column-sum pass (one iteration's numerator)
__global__ void sk_colsum(const float* __restrict__ se, const int* __restrict__ gt,
                          const float* __restrict__ u, float* __restrict__ partials,
                          int iter, int nblk, int N) {
  __shared__ float Sl[KMP];
  const int t = threadIdx.x;
  if (t < KMP) Sl[t] = 0.f;
  __syncthreads();
  const int n = blockIdx.x * 256 + t;
  if (n < N) {
    const int b10 = gt[n] * 10;
    float e[10];
#pragma unroll
    for (int m = 0; m < 10; ++m) e[m] = expf(se[(size_t)n * 10 + m] / 0.05f);
    float a = 1.f;
    if (iter > 0) {
      float s = 0.f;
#pragma unroll
      for (int m = 0; m < 10; ++m) s += e[m] * u[b10 + m];
      a = (s > 0.f) ? 1.f / s : 0.f;
    }
#pragma unroll
    for (int m = 0; m < 10; ++m) atomicAdd(&Sl[b10 + m], a * e[m]);
  }
  __syncthreads();
  if (t < KM) partials[(size_t)t * nblk + blockIdx.x] = Sl[t];
}

__global__ void sk_reduce(const float* __restrict__ partials, float* __restrict__ u,
                          int nblk) {
  const int j = blockIdx.x, lane = threadIdx.x;
  double s = 0.0;
  for (int b = lane; b < nblk; b += 64) s += (double)partials[(size_t)j * nblk + b];
  s = wred_sumd(s);
  if (lane == 0) u[j] = (s > 0.0) ? (float)(1.0 / (10.0 * s)) : 0.f;
}

__global__ void sk_final(const float* __restrict__ se, const int* __restrict__ gt,
                         const float* __restrict__ u, const int* __restrict__ flags,
                         float* __restrict__ ptgt, int* __restrict__ list,
                         int* __restrict__ cnt, int* __restrict__ n_km, int N) {
  const int n = blockIdx.x * 256 + threadIdx.x;
  if (n >= N) return;
  const int g0 = gt[n], b10 = g0 * 10;
  float best = -1.f;
  int bi = 0;
#pragma unroll
  for (int m = 0; m < 10; ++m) {
    const float v = expf(se[(size_t)n * 10 + m] / 0.05f) * u[b10 + m];
    if (v > best) { best = v; bi = m; }
  }
  ptgt[n] = (float)(bi + 10 * g0);
  if (flags[n]) {
    atomicAdd(&n_km[b10 + bi], 1);
    const int p = atomicAdd(cnt, 1);
    list[p] = n | (bi << 20) | (g0 << 24);
  }
}

// ---------------- f accumulation over correct pixels (wave per pixel)
__global__ void f_accum(const float* __restrict__ x, const float* __restrict__ fg,
                        const float* __restrict__ fb, const int* __restrict__ list,
                        const int* __restrict__ cnt, float* __restrict__ f) {
  const int lane = threadIdx.x & 63;
  const int wid = (blockIdx.x * blockDim.x + threadIdx.x) >> 6;
  const int nw = (gridDim.x * blockDim.x) >> 6;
  const int total = *cnt;
  for (int i = wid; i < total; i += nw) {
    const int packed = list[i];
    const int n = packed & 0xFFFFF;
    const int m = (packed >> 20) & 0xF;
    const int k = (packed >> 24) & 0x1F;
    float xv[12];
    float s0 = 0.f, q = 0.f;
#pragma unroll
    for (int jj = 0; jj < 12; ++jj) {
      const int d2 = lane + 64 * jj;
      xv[jj] = (d2 < D) ? x[(size_t)n * D + d2] : 0.f;
      s0 += xv[jj];
      q = fmaf(xv[jj], xv[jj], q);
    }
    s0 = wred_sum(s0);
    q = wred_sum(q);
    const float mu = s0 / 720.f;
    const float var = q / 720.f - mu * mu;
    const float rs = 1.f / sqrtf(var + 1e-5f);
    float cv[12];
    float l2 = 0.f;
#pragma unroll
    for (int jj = 0; jj < 12; ++jj) {
      const int d2 = lane + 64 * jj;
      if (d2 < D) {
        cv[jj] = (xv[jj] - mu) * rs * fg[d2] + fb[d2];
        l2 = fmaf(cv[jj], cv[jj], l2);
      } else {
        cv[jj] = 0.f;
      }
    }
    l2 = wred_sum(l2);
    const float il = 1.f / fmaxf(sqrtf(l2), 1e-12f);
    float* frow = &f[(size_t)(k * 10 + m) * D];
#pragma unroll
    for (int jj = 0; jj < 12; ++jj) {
      const int d2 = lane + 64 * jj;
      if (d2 < D) atomicAdd(&frow[d2], cv[jj] * il);
    }
  }
}

// ---------------- prototype update (one wave per proto row)
__global__ void protos_out(const float* __restrict__ pr, const float* __restrict__ f,
                           const int* __restrict__ n_km, float* __restrict__ out) {
  const int j = blockIdx.x, lane = threadIdx.x;
  float pv[12], fv[12];
  float sp = 0.f, sf = 0.f;
#pragma unroll
  for (int jj = 0; jj < 12; ++jj) {
    const int d2 = lane + 64 * jj;
    pv[jj] = (d2 < D) ? pr[(size_t)j * D + d2] : 0.f;
    fv[jj] = (d2 < D) ? f[(size_t)j * D + d2] : 0.f;
    sp = fmaf(pv[jj], pv[jj], sp);
    sf = fmaf(fv[jj], fv[jj], sf);
  }
  sp = wred_sum(sp);
  sf = wred_sum(sf);
  const float ip = 1.f / fmaxf(sqrtf(sp), 1e-12f);
  const float iff = 1.f / fmaxf(sqrtf(sf), 1e-12f);
  const bool valid = n_km[j] > 0;
  float vv[12];
  float sv = 0.f;
#pragma unroll
  for (int jj = 0; jj < 12; ++jj) {
    const float ph = pv[jj] * ip;
    vv[jj] = valid ? (0.999f * ph + 0.001f * (fv[jj] * iff)) : ph;
    sv = fmaf(vv[jj], vv[jj], sv);
  }
  sv = wred_sum(sv);
  const float ivv = 1.f / fmaxf(sqrtf(sv), 1e-12f);
#pragma unroll
  for (int jj = 0; jj < 12; ++jj) {
    const int d2 = lane + 64 * jj;
    if (d2 < D) out[(size_t)j * D + d2] = vv[jj] * ivv;
  }
}

extern "C" void kernel_launch(void* const* d_in, const int* in_sizes, int n_in,
                              void* d_out, int out_size, void* d_ws, size_t ws_size,
                              hipStream_t stream) {
  const float* x = (const float*)d_in[0];
  const float* protos = (const float*)d_in[1];
  const float* fn_g = (const float*)d_in[2];
  const float* fn_b = (const float*)d_in[3];
  const float* mn_g = (const float*)d_in[4];
  const float* mn_b = (const float*)d_in[5];
  const float* pn_g = (const float*)d_in[6];
  const float* pn_b = (const float*)d_in[7];
  const int* gt = (const int*)d_in[8];
  const int N = in_sizes[0] / D;

  float* out_seg = (float*)d_out;
  float* contrast = out_seg + (size_t)N * NCLS;
  float* ptgt = contrast + (size_t)N * KM;
  float* pnew = ptgt + (size_t)N;

  char* ws = (char*)d_ws;
  size_t off = 0;
  auto alloc = [&](size_t bytes) {
    char* p = ws + off;
    off = (off + bytes + 255) & ~(size_t)255;
    return p;
  };
  const int nblk = (N + 255) / 256;
  ushort* pgtb = (ushort*)alloc((size_t)NCHK * 6144 * 2);  // 552960 B
  float* Av = (float*)alloc(KMP * 4);
  float* Bv = (float*)alloc(KMP * 4);
  float* G2 = (float*)alloc(D * 4);
  float* GB = (float*)alloc(D * 4);
  float* C3 = (float*)alloc(4 * 4);
  float* se = (float*)alloc((size_t)N * 10 * 4);
  float* partials = (float*)alloc((size_t)KM * nblk * 4);
  float* u = (float*)alloc(KMP * 4);
  float* f = (float*)alloc((size_t)KM * D * 4);
  int* n_km = (int*)alloc(KMP * 4);
  int* flags = (int*)alloc((size_t)N * 4);
  int* list = (int*)alloc((size_t)N * 4);
  int* cnt = (int*)alloc(256);

  hipMemsetAsync(f, 0, (size_t)KM * D * 4, stream);
  hipMemsetAsync(n_km, 0, KMP * 4, stream);
  hipMemsetAsync(cnt, 0, 4, stream);

  prep_gb<<<1, 256, 0, stream>>>(fn_g, fn_b, G2, GB, C3);
  proto_prep<<<KMP, 64, 0, stream>>>(protos, fn_g, fn_b, pgtb, Av, Bv);
  gemm_main<<<N / BM, 256, 0, stream>>>(x, pgtb, Av, Bv, G2, GB, C3, gt, out_seg,
                                        contrast, se, flags, mn_g, mn_b, pn_g,
                                        pn_b, N);
  for (int it = 0; it < 3; ++it) {
    sk_colsum<<<nblk, 256, 0, stream>>>(se, gt, u, partials, it, nblk, N);
    sk_reduce<<<KM, 64, 0, stream>>>(partials, u, nblk);
  }
  sk_final<<<nblk, 256, 0, stream>>>(se, gt, u, flags, ptgt, list, cnt, n_km, N);
  f_accum<<<256, 256, 0, stream>>>(x, fn_g, fn_b, list, cnt, f);
  protos_out<<<KM, 64, 0, stream>>>(protos, f, n_km, pnew);
}